// Round 11
// baseline (234.286 us; speedup 1.0000x reference)
//
#include <hip/hip_runtime.h>
#include <hip/hip_bf16.h>

#define NT 4096
#define HD 2048
#define NE 16
#define ID 512
#define TWO_I 1024
#define PITCH 72     // padded bf16 P-tile pitch in ushorts (144B, 16B-aligned rows)
#define MAXITEMS 47  // worst case: ceil(4081/128)=32 + 15 singleton experts

typedef __attribute__((ext_vector_type(8))) short bf16x8_t;
typedef __attribute__((ext_vector_type(4))) float f32x4_t;

__device__ __forceinline__ unsigned short f2bf(float f) {
  union { float f; unsigned int u; } v; v.f = f;
  unsigned int r = v.u + 0x7fffu + ((v.u >> 16) & 1u);
  return (unsigned short)(r >> 16);
}
__device__ __forceinline__ unsigned pk2(unsigned short a, unsigned short b) {
  return (unsigned)a | ((unsigned)b << 16);
}
// async global->LDS: LDS dest = wave-uniform base + lane*16; global src is PER-LANE
__device__ __forceinline__ void gl_lds16(const void* g, void* l) {
  __builtin_amdgcn_global_load_lds(
      (const __attribute__((address_space(1))) unsigned int*)g,
      (__attribute__((address_space(3))) unsigned int*)l, 16, 0, 0);
}

// ---------------- weight prep: f32 [k][col] -> bf16 blocked [cb][k][64] ----------------
__global__ __launch_bounds__(256) void k_prep_gu(const float* __restrict__ gup,
                                                 unsigned short* __restrict__ wgb) {
  int e = blockIdx.y, k0 = blockIdx.x * 32;   // grid (64, 16)
  int t = threadIdx.x;
  int cb = t >> 4, c = (t & 15) * 4;
  const float* src = gup + ((size_t)e * HD + k0) * TWO_I + t * 4;
  unsigned short* dst = wgb + (((size_t)e * 16 + cb) * HD + k0) * 64 + c;
#pragma unroll 4
  for (int j = 0; j < 32; ++j) {
    float4 v = *(const float4*)src; src += TWO_I;
    uint2 p; p.x = pk2(f2bf(v.x), f2bf(v.y)); p.y = pk2(f2bf(v.z), f2bf(v.w));
    *(uint2*)dst = p; dst += 64;
  }
}
__global__ __launch_bounds__(256) void k_prep_dn(const float* __restrict__ dwn,
                                                 unsigned short* __restrict__ wdb) {
  int e = blockIdx.y, k0 = blockIdx.x * 32;   // grid (16, 16)
  int t = threadIdx.x;
  int cb = t >> 3, c = (t & 7) * 8;
  const float* src = dwn + ((size_t)e * ID + k0) * HD + t * 8;
  unsigned short* dst = wdb + (((size_t)e * 32 + cb) * ID + k0) * 64 + c;
#pragma unroll 4
  for (int j = 0; j < 32; ++j) {
    float4 v0 = *(const float4*)src;
    float4 v1 = *(const float4*)(src + 4); src += HD;
    uint4 p;
    p.x = pk2(f2bf(v0.x), f2bf(v0.y)); p.y = pk2(f2bf(v0.z), f2bf(v0.w));
    p.z = pk2(f2bf(v1.x), f2bf(v1.y)); p.w = pk2(f2bf(v1.z), f2bf(v1.w));
    *(uint4*)dst = p; dst += 64;
  }
}

// ---------------- cast x (f32 -> bf16) ----------------
__global__ void k_cast_x(const float* __restrict__ x, unsigned short* __restrict__ xb) {
  size_t i = ((size_t)blockIdx.x * 256 + threadIdx.x) * 8;
  float4 a = *(const float4*)(x + i);
  float4 b = *(const float4*)(x + i + 4);
  uint4 pk;
  pk.x = pk2(f2bf(a.x), f2bf(a.y)); pk.y = pk2(f2bf(a.z), f2bf(a.w));
  pk.z = pk2(f2bf(b.x), f2bf(b.y)); pk.w = pk2(f2bf(b.z), f2bf(b.w));
  *(uint4*)(xb + i) = pk;
}

// ---------------- routing ----------------
__global__ void k_route(const float* __restrict__ mu, const int* __restrict__ tok,
                        const float* __restrict__ wr, int* __restrict__ eid) {
  int t = blockIdx.x;
  int tid = threadIdx.x;
  float p[NE];
#pragma unroll
  for (int e = 0; e < NE; ++e) p[e] = 0.f;
  const float* m = mu + (size_t)t * HD;
  for (int h = tid; h < HD; h += 256) {
    float mv = m[h];
#pragma unroll
    for (int e = 0; e < NE; ++e) p[e] += mv * wr[e * HD + h];
  }
#pragma unroll
  for (int e = 0; e < NE; ++e) {
    float v = p[e];
#pragma unroll
    for (int s = 32; s; s >>= 1) v += __shfl_xor(v, s, 64);
    p[e] = v;
  }
  __shared__ float red[4][NE];
  int lane = tid & 63, wv = tid >> 6;
  if (lane == 0) {
#pragma unroll
    for (int e = 0; e < NE; ++e) red[wv][e] = p[e];
  }
  __syncthreads();
  if (tid == 0) {
    int tk = tok[t];
    if (tk < 0) tk = 0;
    if (tk > 31999) tk = 31999;
    int base = tk & 15;
    float best = -3.0e38f; int bi = 0;
    for (int e = 0; e < NE; ++e) {
      float v = red[0][e] + red[1][e] + red[2][e] + red[3][e];
      if (e == base) v += 10.0f;
      if (v > best) { best = v; bi = e; }
    }
    eid[t] = bi;
  }
}

// ---------------- bucket tokens + worklist ----------------
__global__ void k_init(int* counts, int* cursors) {
  int i = threadIdx.x;
  if (i < NE) { counts[i] = 0; cursors[i] = 0; }
}
__global__ void k_hist(const int* __restrict__ eid, int* __restrict__ counts) {
  int t = blockIdx.x * 256 + threadIdx.x;
  if (t < NT) atomicAdd(&counts[eid[t]], 1);
}
__global__ void k_scan(const int* __restrict__ counts, int* __restrict__ offsets,
                       int* __restrict__ cursors, int* __restrict__ wk) {
  if (threadIdx.x == 0) {
    int s = 0;
    for (int e = 0; e < NE; ++e) { offsets[e] = s; cursors[e] = s; s += counts[e]; }
    offsets[NE] = s;
    int n = 0;
    for (int e = 0; e < NE; ++e) {
      int tiles = (counts[e] + 127) >> 7;
      for (int m = 0; m < tiles; ++m) { wk[n++] = e | (m << 8); }
    }
    wk[MAXITEMS] = n;
  }
}
__global__ void k_scatter(const int* __restrict__ eid, int* __restrict__ cursors,
                          int* __restrict__ tlist) {
  int t = blockIdx.x * 256 + threadIdx.x;
  if (t < NT) {
    int e = eid[t];
    int pos = atomicAdd(&cursors[e], 1);
    tlist[pos] = t;
  }
}

// ---------------- gemm1: h = silu(x@Wg) * (x@Wu) ----------------
// B from blocked bf16 wgb: per K-step each wave gl_lds's 4 CONTIGUOUS 1KB chunks
// (global src per-lane: base + lane*16B). 1-barrier pipeline, wave-local
// transpose, A direct-to-reg. Block: 128 tokens x 64 h-cols.
__global__ __launch_bounds__(256, 2) void k_gemm1(
    const unsigned short* __restrict__ xb, const unsigned short* __restrict__ wgb,
    const int* __restrict__ offsets, const int* __restrict__ tlist,
    const int* __restrict__ wk, unsigned short* __restrict__ hbuf) {
  int item = blockIdx.y;
  if (item >= wk[MAXITEMS]) return;
  int w = wk[item];
  int e = w & 255, tb = (w >> 8) * 128;
  int off = offsets[e], cnt = offsets[e + 1] - off;
  int cx = blockIdx.x;
  int c0 = cx * 64;

  __shared__ unsigned short Bb[2][2][64 * 64];   // [buf][g/u][k][64] bf16 (32KB)
  __shared__ unsigned short Pb[2][128 * PITCH];  // [buf][col][k] bf16 (36KB)
  __shared__ int ltok[128];

  int tid = threadIdx.x, lane = tid & 63, wv = tid >> 6;
  if (tid < 128) { int r = tb + tid; if (r > cnt - 1) r = cnt - 1; ltok[tid] = tlist[off + r]; }
  __syncthreads();

  int lr = lane & 15, hi = lane >> 4, mb = wv * 32;
  const unsigned short* aRow0 = xb + (size_t)ltok[mb + lr] * HD + hi * 8;
  const unsigned short* aRow1 = xb + (size_t)ltok[mb + 16 + lr] * HD + hi * 8;

  const unsigned short* gS0;
  const unsigned short* gS1;
  const unsigned short* uS0;
  const unsigned short* uS1;
  {
    const unsigned short* gbase = wgb + ((size_t)(e * 16 + cx) * HD) * 64;
    const unsigned short* ubase = wgb + ((size_t)(e * 16 + 8 + cx) * HD) * 64;
    int lo = lane * 8;  // per-lane 16B offset within the 1KB chunk
    gS0 = gbase + (wv * 16) * 64 + lo;      gS1 = gbase + (wv * 16 + 8) * 64 + lo;
    uS0 = ubase + (wv * 16) * 64 + lo;      uS1 = ubase + (wv * 16 + 8) * 64 + lo;
  }

#define STAGEB(BUF) do { \
  gl_lds16(gS0, &Bb[BUF][0][(wv * 16) * 64]);     gS0 += 4096; \
  gl_lds16(gS1, &Bb[BUF][0][(wv * 16 + 8) * 64]); gS1 += 4096; \
  gl_lds16(uS0, &Bb[BUF][1][(wv * 16) * 64]);     uS0 += 4096; \
  gl_lds16(uS1, &Bb[BUF][1][(wv * 16 + 8) * 64]); uS1 += 4096; \
} while (0)

  bf16x8_t A0[4], A1[4];
#define LOADA(SET, KT) do { \
  SET[0] = *(const bf16x8_t*)(aRow0 + (KT) * 64); \
  SET[1] = *(const bf16x8_t*)(aRow0 + (KT) * 64 + 32); \
  SET[2] = *(const bf16x8_t*)(aRow1 + (KT) * 64); \
  SET[3] = *(const bf16x8_t*)(aRow1 + (KT) * 64 + 32); \
} while (0)

// wave-local transpose: wave wv owns k-rows [wv*16,wv*16+16) of BOTH tiles
// (exactly the rows its own gl_lds staged). Pure pack, no cvt.
#define TRANSP(BUF) do { \
  int T_ = lane >> 5, c2_ = (lane & 31) * 2; \
  const unsigned short* b_ = &Bb[BUF][T_][(wv * 16) * 64 + c2_]; \
  unsigned v_[16]; \
  _Pragma("unroll") for (int j = 0; j < 16; ++j) v_[j] = *(const unsigned*)(b_ + j * 64); \
  uint4 lo0_, lo1_, hi0_, hi1_; \
  lo0_.x = (v_[0] & 0xffffu) | (v_[1] << 16);  lo0_.y = (v_[2] & 0xffffu) | (v_[3] << 16); \
  lo0_.z = (v_[4] & 0xffffu) | (v_[5] << 16);  lo0_.w = (v_[6] & 0xffffu) | (v_[7] << 16); \
  lo1_.x = (v_[8] & 0xffffu) | (v_[9] << 16);  lo1_.y = (v_[10] & 0xffffu) | (v_[11] << 16); \
  lo1_.z = (v_[12] & 0xffffu) | (v_[13] << 16); lo1_.w = (v_[14] & 0xffffu) | (v_[15] << 16); \
  hi0_.x = (v_[0] >> 16) | (v_[1] & 0xffff0000u);  hi0_.y = (v_[2] >> 16) | (v_[3] & 0xffff0000u); \
  hi0_.z = (v_[4] >> 16) | (v_[5] & 0xffff0000u);  hi0_.w = (v_[6] >> 16) | (v_[7] & 0xffff0000u); \
  hi1_.x = (v_[8] >> 16) | (v_[9] & 0xffff0000u);  hi1_.y = (v_[10] >> 16) | (v_[11] & 0xffff0000u); \
  hi1_.z = (v_[12] >> 16) | (v_[13] & 0xffff0000u); hi1_.w = (v_[14] >> 16) | (v_[15] & 0xffff0000u); \
  unsigned short* p0_ = &Pb[BUF][(T_ * 64 + c2_) * PITCH + wv * 16]; \
  *(uint4*)p0_ = lo0_; *(uint4*)(p0_ + 8) = lo1_; \
  *(uint4*)(p0_ + PITCH) = hi0_; *(uint4*)(p0_ + PITCH + 8) = hi1_; \
} while (0)

  f32x4_t zero = {0.f, 0.f, 0.f, 0.f};
  f32x4_t accg[2][4], accu[2][4];
#pragma unroll
  for (int m = 0; m < 2; ++m)
#pragma unroll
    for (int n = 0; n < 4; ++n) { accg[m][n] = zero; accu[m][n] = zero; }

#define MFMA_PH(BUF, SET) do { \
  __builtin_amdgcn_s_setprio(1); \
  _Pragma("unroll") for (int kk = 0; kk < 2; ++kk) { \
    int klo = kk * 32 + hi * 8; \
    bf16x8_t a0 = SET[kk], a1 = SET[2 + kk]; \
    _Pragma("unroll") for (int n = 0; n < 4; ++n) { \
      bf16x8_t bg = *(bf16x8_t*)&Pb[BUF][(n * 16 + lr) * PITCH + klo]; \
      bf16x8_t bu = *(bf16x8_t*)&Pb[BUF][(64 + n * 16 + lr) * PITCH + klo]; \
      accg[0][n] = __builtin_amdgcn_mfma_f32_16x16x32_bf16(a0, bg, accg[0][n], 0, 0, 0); \
      accu[0][n] = __builtin_amdgcn_mfma_f32_16x16x32_bf16(a0, bu, accu[0][n], 0, 0, 0); \
      accg[1][n] = __builtin_amdgcn_mfma_f32_16x16x32_bf16(a1, bg, accg[1][n], 0, 0, 0); \
      accu[1][n] = __builtin_amdgcn_mfma_f32_16x16x32_bf16(a1, bu, accu[1][n], 0, 0, 0); \
    } \
  } \
  __builtin_amdgcn_s_setprio(0); \
} while (0)

#define SUBSTEP(KT, BUF, SET, VMC) do { \
  asm volatile("s_waitcnt vmcnt(" #VMC ")" ::: "memory"); \
  __builtin_amdgcn_sched_barrier(0); \
  TRANSP(BUF); \
  asm volatile("s_waitcnt lgkmcnt(0)" ::: "memory"); \
  __builtin_amdgcn_sched_barrier(0); \
  __builtin_amdgcn_s_barrier(); \
  MFMA_PH(BUF, SET); \
  if ((KT) + 2 < 32) { LOADA(SET, (KT) + 2); STAGEB(BUF); } \
} while (0)

  LOADA(A0, 0); STAGEB(0);
  LOADA(A1, 1); STAGEB(1);

  for (int kt2 = 0; kt2 < 15; ++kt2) {
    SUBSTEP(2 * kt2, 0, A0, 8);
    SUBSTEP(2 * kt2 + 1, 1, A1, 8);
  }
  SUBSTEP(30, 0, A0, 8);
  SUBSTEP(31, 1, A1, 0);

#undef SUBSTEP
#undef MFMA_PH
#undef TRANSP
#undef LOADA
#undef STAGEB

  int rq = hi * 4;
#pragma unroll
  for (int m = 0; m < 2; ++m)
#pragma unroll
    for (int n = 0; n < 4; ++n)
#pragma unroll
      for (int j = 0; j < 4; ++j) {
        int r = tb + mb + m * 16 + rq + j;
        if (r < cnt) {
          float g = accg[m][n][j], u = accu[m][n][j];
          float hv = (g / (1.f + __expf(-g))) * u;
          hbuf[(size_t)(off + r) * ID + c0 + n * 16 + lr] = f2bf(hv);
        }
      }
}

// ---------------- gemm2: out = h @ Wd ----------------
// Block: 128 tokens x 128 out-cols (cb 2cx, 2cx+1); 8 K-steps.
__global__ __launch_bounds__(256, 2) void k_gemm2(
    const unsigned short* __restrict__ hbuf, const unsigned short* __restrict__ wdb,
    const int* __restrict__ offsets, const int* __restrict__ tlist,
    const int* __restrict__ wk, float* __restrict__ out) {
  int item = blockIdx.y;
  if (item >= wk[MAXITEMS]) return;
  int w = wk[item];
  int e = w & 255, tb = (w >> 8) * 128;
  int off = offsets[e], cnt = offsets[e + 1] - off;
  int cx = blockIdx.x;
  int c0 = cx * 128;

  __shared__ unsigned short Bb[2][2][64 * 64];
  __shared__ unsigned short Pb[2][128 * PITCH];

  int tid = threadIdx.x, lane = tid & 63, wv = tid >> 6;
  int lr = lane & 15, hi = lane >> 4, mb = wv * 32;

  int r0 = tb + mb + lr;      if (r0 > cnt - 1) r0 = cnt - 1;
  int r1 = tb + mb + 16 + lr; if (r1 > cnt - 1) r1 = cnt - 1;
  const unsigned short* aRow0 = hbuf + (size_t)(off + r0) * ID + hi * 8;
  const unsigned short* aRow1 = hbuf + (size_t)(off + r1) * ID + hi * 8;

  const unsigned short* gS0;
  const unsigned short* gS1;
  const unsigned short* uS0;
  const unsigned short* uS1;
  {
    const unsigned short* b0 = wdb + ((size_t)(e * 32 + 2 * cx) * ID) * 64;
    const unsigned short* b1 = wdb + ((size_t)(e * 32 + 2 * cx + 1) * ID) * 64;
    int lo = lane * 8;  // per-lane 16B offset
    gS0 = b0 + (wv * 16) * 64 + lo;  gS1 = b0 + (wv * 16 + 8) * 64 + lo;
    uS0 = b1 + (wv * 16) * 64 + lo;  uS1 = b1 + (wv * 16 + 8) * 64 + lo;
  }

#define STAGEB(BUF) do { \
  gl_lds16(gS0, &Bb[BUF][0][(wv * 16) * 64]);     gS0 += 4096; \
  gl_lds16(gS1, &Bb[BUF][0][(wv * 16 + 8) * 64]); gS1 += 4096; \
  gl_lds16(uS0, &Bb[BUF][1][(wv * 16) * 64]);     uS0 += 4096; \
  gl_lds16(uS1, &Bb[BUF][1][(wv * 16 + 8) * 64]); uS1 += 4096; \
} while (0)

  bf16x8_t A0[4], A1[4];
#define LOADA(SET, KT) do { \
  SET[0] = *(const bf16x8_t*)(aRow0 + (KT) * 64); \
  SET[1] = *(const bf16x8_t*)(aRow0 + (KT) * 64 + 32); \
  SET[2] = *(const bf16x8_t*)(aRow1 + (KT) * 64); \
  SET[3] = *(const bf16x8_t*)(aRow1 + (KT) * 64 + 32); \
} while (0)

#define TRANSP(BUF) do { \
  int T_ = lane >> 5, c2_ = (lane & 31) * 2; \
  const unsigned short* b_ = &Bb[BUF][T_][(wv * 16) * 64 + c2_]; \
  unsigned v_[16]; \
  _Pragma("unroll") for (int j = 0; j < 16; ++j) v_[j] = *(const unsigned*)(b_ + j * 64); \
  uint4 lo0_, lo1_, hi0_, hi1_; \
  lo0_.x = (v_[0] & 0xffffu) | (v_[1] << 16);  lo0_.y = (v_[2] & 0xffffu) | (v_[3] << 16); \
  lo0_.z = (v_[4] & 0xffffu) | (v_[5] << 16);  lo0_.w = (v_[6] & 0xffffu) | (v_[7] << 16); \
  lo1_.x = (v_[8] & 0xffffu) | (v_[9] << 16);  lo1_.y = (v_[10] & 0xffffu) | (v_[11] << 16); \
  lo1_.z = (v_[12] & 0xffffu) | (v_[13] << 16); lo1_.w = (v_[14] & 0xffffu) | (v_[15] << 16); \
  hi0_.x = (v_[0] >> 16) | (v_[1] & 0xffff0000u);  hi0_.y = (v_[2] >> 16) | (v_[3] & 0xffff0000u); \
  hi0_.z = (v_[4] >> 16) | (v_[5] & 0xffff0000u);  hi0_.w = (v_[6] >> 16) | (v_[7] & 0xffff0000u); \
  hi1_.x = (v_[8] >> 16) | (v_[9] & 0xffff0000u);  hi1_.y = (v_[10] >> 16) | (v_[11] & 0xffff0000u); \
  hi1_.z = (v_[12] >> 16) | (v_[13] & 0xffff0000u); hi1_.w = (v_[14] >> 16) | (v_[15] & 0xffff0000u); \
  unsigned short* p0_ = &Pb[BUF][(T_ * 64 + c2_) * PITCH + wv * 16]; \
  *(uint4*)p0_ = lo0_; *(uint4*)(p0_ + 8) = lo1_; \
  *(uint4*)(p0_ + PITCH) = hi0_; *(uint4*)(p0_ + PITCH + 8) = hi1_; \
} while (0)

  f32x4_t zero = {0.f, 0.f, 0.f, 0.f};
  f32x4_t acc[2][8];
#pragma unroll
  for (int m = 0; m < 2; ++m)
#pragma unroll
    for (int n = 0; n < 8; ++n) acc[m][n] = zero;

#define MFMA_PH(BUF, SET) do { \
  __builtin_amdgcn_s_setprio(1); \
  _Pragma("unroll") for (int kk = 0; kk < 2; ++kk) { \
    int klo = kk * 32 + hi * 8; \
    bf16x8_t a0 = SET[kk], a1 = SET[2 + kk]; \
    _Pragma("unroll") for (int n = 0; n < 8; ++n) { \
      bf16x8_t b = *(bf16x8_t*)&Pb[BUF][(n * 16 + lr) * PITCH + klo]; \
      acc[0][n] = __builtin_amdgcn_mfma_f32_16x16x32_bf16(a0, b, acc[0][n], 0, 0, 0); \
      acc[1][n] = __builtin_amdgcn_mfma_f32_16x16x32_bf16(a1, b, acc[1][n], 0, 0, 0); \
    } \
  } \
  __builtin_amdgcn_s_setprio(0); \
} while (0)

#define SUBSTEP(KT, BUF, SET, VMC) do { \
  asm volatile("s_waitcnt vmcnt(" #VMC ")" ::: "memory"); \
  __builtin_amdgcn_sched_barrier(0); \
  TRANSP(BUF); \
  asm volatile("s_waitcnt lgkmcnt(0)" ::: "memory"); \
  __builtin_amdgcn_sched_barrier(0); \
  __builtin_amdgcn_s_barrier(); \
  MFMA_PH(BUF, SET); \
  if ((KT) + 2 < 8) { LOADA(SET, (KT) + 2); STAGEB(BUF); } \
} while (0)

  LOADA(A0, 0); STAGEB(0);
  LOADA(A1, 1); STAGEB(1);

  SUBSTEP(0, 0, A0, 8);
  SUBSTEP(1, 1, A1, 8);
  SUBSTEP(2, 0, A0, 8);
  SUBSTEP(3, 1, A1, 8);
  SUBSTEP(4, 0, A0, 8);
  SUBSTEP(5, 1, A1, 8);
  SUBSTEP(6, 0, A0, 8);
  SUBSTEP(7, 1, A1, 0);

#undef SUBSTEP
#undef MFMA_PH
#undef TRANSP
#undef LOADA
#undef STAGEB

  int rq = hi * 4;
#pragma unroll
  for (int m = 0; m < 2; ++m)
#pragma unroll
    for (int n = 0; n < 8; ++n)
#pragma unroll
      for (int j = 0; j < 4; ++j) {
        int r = tb + mb + m * 16 + rq + j;
        if (r < cnt) {
          out[(size_t)tlist[off + r] * HD + c0 + n * 16 + lr] = acc[m][n][j];
        }
      }
}

extern "C" void kernel_launch(void* const* d_in, const int* in_sizes, int n_in,
                              void* d_out, int out_size, void* d_ws, size_t ws_size,
                              hipStream_t stream) {
  (void)in_sizes; (void)n_in; (void)out_size; (void)ws_size;
  const float* x   = (const float*)d_in[0];
  const int*   tok = (const int*)d_in[1];
  const float* mu  = (const float*)d_in[2];
  const float* gup = (const float*)d_in[3];
  const float* dwn = (const float*)d_in[4];
  const float* wr  = (const float*)d_in[5];
  float* out = (float*)d_out;

  char* ws = (char*)d_ws;
  int* eid     = (int*)ws;
  int* tlist   = (int*)(ws + 16384);
  int* counts  = (int*)(ws + 32768);
  int* offsets = (int*)(ws + 32896);
  int* cursors = (int*)(ws + 33024);
  int* wk      = (int*)(ws + 33152);
  unsigned short* xb   = (unsigned short*)(ws + 65536);                    // 16 MB
  unsigned short* hbuf = (unsigned short*)(ws + 65536 + 16777216);         // 4 MB
  unsigned short* wgb  = (unsigned short*)(ws + 65536 + 16777216 + 4194304);          // 64 MB
  unsigned short* wdb  = (unsigned short*)(ws + 65536 + 16777216 + 4194304 + 67108864); // 32 MB

  k_prep_gu<<<dim3(64, 16), 256, 0, stream>>>(gup, wgb);
  k_prep_dn<<<dim3(16, 16), 256, 0, stream>>>(dwn, wdb);
  k_cast_x <<<4096, 256, 0, stream>>>(x, xb);
  k_route  <<<NT, 256, 0, stream>>>(mu, tok, wr, eid);
  k_init   <<<1, 64, 0, stream>>>(counts, cursors);
  k_hist   <<<16, 256, 0, stream>>>(eid, counts);
  k_scan   <<<1, 64, 0, stream>>>(counts, offsets, cursors, wk);
  k_scatter<<<16, 256, 0, stream>>>(eid, cursors, tlist);
  k_gemm1  <<<dim3(8, MAXITEMS), 256, 0, stream>>>(xb, wgb, offsets, tlist, wk, hbuf);
  k_gemm2  <<<dim3(16, MAXITEMS), 256, 0, stream>>>(hbuf, wdb, offsets, tlist, wk, out);
}

// Round 12
// 231.514 us; speedup vs baseline: 1.0120x; 1.0120x over previous
//
#include <hip/hip_runtime.h>
#include <hip/hip_bf16.h>

#define NT 4096
#define HD 2048
#define NE 16
#define ID 512
#define TWO_I 1024
#define MAXITEMS 47  // worst case: ceil(4081/128)=32 + 15 singleton experts

typedef __attribute__((ext_vector_type(8))) short bf16x8_t;
typedef __attribute__((ext_vector_type(4))) float f32x4_t;

__device__ __forceinline__ unsigned short f2bf(float f) {
  union { float f; unsigned int u; } v; v.f = f;
  unsigned int r = v.u + 0x7fffu + ((v.u >> 16) & 1u);
  return (unsigned short)(r >> 16);
}
__device__ __forceinline__ unsigned pk2(unsigned short a, unsigned short b) {
  return (unsigned)a | ((unsigned)b << 16);
}
// async global->LDS: LDS dest = wave-uniform base + lane*16; global src PER-LANE
__device__ __forceinline__ void gl_lds16(const void* g, void* l) {
  __builtin_amdgcn_global_load_lds(
      (const __attribute__((address_space(1))) unsigned int*)g,
      (__attribute__((address_space(3))) unsigned int*)l, 16, 0, 0);
}

// ============ weight prep: f32 [k][col] -> bf16 TRANSPOSED+SWIZZLED tiles =========
// layout: [e][cb][kt][ tile 64col x 64k ]; tile elem (c,k) at
//   c*64 + ((k>>3)^(c&7))*8 + (k&7)   (T2 16B-chunk XOR swizzle)
// GEMM then stages each 8KB tile LINEARLY via gl_lds and MFMA-reads swizzled.
__global__ __launch_bounds__(256) void k_prep_gu(const float* __restrict__ gup,
                                                 unsigned short* __restrict__ wgb) {
  int kt = blockIdx.x, e = blockIdx.y;           // grid (32, 16)
  int K0 = kt * 64;
  int t = threadIdx.x, w = t >> 6, lane = t & 63;
  __shared__ unsigned short L[64][264];          // 64 k x 256 cols (+pad)
  for (int q = 0; q < 4; ++q) {
    for (int rd = 0; rd < 16; ++rd) {
      int row = rd * 4 + w;
      const float* s = gup + ((size_t)e * HD + K0 + row) * TWO_I + q * 256 + lane * 4;
      float4 v = *(const float4*)s;
      uint2 p; p.x = pk2(f2bf(v.x), f2bf(v.y)); p.y = pk2(f2bf(v.z), f2bf(v.w));
      *(uint2*)&L[row][lane * 4] = p;
    }
    __syncthreads();
    int cbl = (t >> 5) & 3, c = (t & 31) * 2, kh = t >> 7;
    int cb = q * 4 + cbl;
    unsigned short* tb = wgb + (((size_t)e * 16 + cb) * 32 + kt) * 4096;
    int cc = cbl * 64 + c;
    for (int j = kh * 4; j < kh * 4 + 4; ++j) {
      unsigned vv[8];
#pragma unroll
      for (int i = 0; i < 8; ++i) vv[i] = *(const unsigned*)&L[j * 8 + i][cc];
      uint4 lo, hi2;
      lo.x = (vv[0] & 0xffffu) | (vv[1] << 16);  lo.y = (vv[2] & 0xffffu) | (vv[3] << 16);
      lo.z = (vv[4] & 0xffffu) | (vv[5] << 16);  lo.w = (vv[6] & 0xffffu) | (vv[7] << 16);
      hi2.x = (vv[0] >> 16) | (vv[1] & 0xffff0000u);  hi2.y = (vv[2] >> 16) | (vv[3] & 0xffff0000u);
      hi2.z = (vv[4] >> 16) | (vv[5] & 0xffff0000u);  hi2.w = (vv[6] >> 16) | (vv[7] & 0xffff0000u);
      *(uint4*)&tb[c * 64 + ((j ^ (c & 7)) * 8)] = lo;
      *(uint4*)&tb[(c + 1) * 64 + ((j ^ ((c + 1) & 7)) * 8)] = hi2;
    }
    __syncthreads();
  }
}
__global__ __launch_bounds__(256) void k_prep_dn(const float* __restrict__ dwn,
                                                 unsigned short* __restrict__ wdb) {
  int kt = blockIdx.x, e = blockIdx.y, half = blockIdx.z;  // grid (8, 16, 2)
  int K0 = kt * 64;
  int t = threadIdx.x, w = t >> 6, lane = t & 63;
  __shared__ unsigned short L[64][264];
  for (int q = 0; q < 4; ++q) {
    for (int rd = 0; rd < 16; ++rd) {
      int row = rd * 4 + w;
      const float* s = dwn + ((size_t)e * ID + K0 + row) * HD + half * 1024 + q * 256 + lane * 4;
      float4 v = *(const float4*)s;
      uint2 p; p.x = pk2(f2bf(v.x), f2bf(v.y)); p.y = pk2(f2bf(v.z), f2bf(v.w));
      *(uint2*)&L[row][lane * 4] = p;
    }
    __syncthreads();
    int cbl = (t >> 5) & 3, c = (t & 31) * 2, kh = t >> 7;
    int cb = half * 16 + q * 4 + cbl;
    unsigned short* tb = wdb + (((size_t)e * 32 + cb) * 8 + kt) * 4096;
    int cc = cbl * 64 + c;
    for (int j = kh * 4; j < kh * 4 + 4; ++j) {
      unsigned vv[8];
#pragma unroll
      for (int i = 0; i < 8; ++i) vv[i] = *(const unsigned*)&L[j * 8 + i][cc];
      uint4 lo, hi2;
      lo.x = (vv[0] & 0xffffu) | (vv[1] << 16);  lo.y = (vv[2] & 0xffffu) | (vv[3] << 16);
      lo.z = (vv[4] & 0xffffu) | (vv[5] << 16);  lo.w = (vv[6] & 0xffffu) | (vv[7] << 16);
      hi2.x = (vv[0] >> 16) | (vv[1] & 0xffff0000u);  hi2.y = (vv[2] >> 16) | (vv[3] & 0xffff0000u);
      hi2.z = (vv[4] >> 16) | (vv[5] & 0xffff0000u);  hi2.w = (vv[6] >> 16) | (vv[7] & 0xffff0000u);
      *(uint4*)&tb[c * 64 + ((j ^ (c & 7)) * 8)] = lo;
      *(uint4*)&tb[(c + 1) * 64 + ((j ^ ((c + 1) & 7)) * 8)] = hi2;
    }
    __syncthreads();
  }
}

// ---------------- cast x (f32 -> bf16) ----------------
__global__ void k_cast_x(const float* __restrict__ x, unsigned short* __restrict__ xb) {
  size_t i = ((size_t)blockIdx.x * 256 + threadIdx.x) * 8;
  float4 a = *(const float4*)(x + i);
  float4 b = *(const float4*)(x + i + 4);
  uint4 pk;
  pk.x = pk2(f2bf(a.x), f2bf(a.y)); pk.y = pk2(f2bf(a.z), f2bf(a.w));
  pk.z = pk2(f2bf(b.x), f2bf(b.y)); pk.w = pk2(f2bf(b.z), f2bf(b.w));
  *(uint4*)(xb + i) = pk;
}

// ---------------- routing ----------------
__global__ void k_route(const float* __restrict__ mu, const int* __restrict__ tok,
                        const float* __restrict__ wr, int* __restrict__ eid) {
  int t = blockIdx.x;
  int tid = threadIdx.x;
  float p[NE];
#pragma unroll
  for (int e = 0; e < NE; ++e) p[e] = 0.f;
  const float* m = mu + (size_t)t * HD;
  for (int h = tid; h < HD; h += 256) {
    float mv = m[h];
#pragma unroll
    for (int e = 0; e < NE; ++e) p[e] += mv * wr[e * HD + h];
  }
#pragma unroll
  for (int e = 0; e < NE; ++e) {
    float v = p[e];
#pragma unroll
    for (int s = 32; s; s >>= 1) v += __shfl_xor(v, s, 64);
    p[e] = v;
  }
  __shared__ float red[4][NE];
  int lane = tid & 63, wv = tid >> 6;
  if (lane == 0) {
#pragma unroll
    for (int e = 0; e < NE; ++e) red[wv][e] = p[e];
  }
  __syncthreads();
  if (tid == 0) {
    int tk = tok[t];
    if (tk < 0) tk = 0;
    if (tk > 31999) tk = 31999;
    int base = tk & 15;
    float best = -3.0e38f; int bi = 0;
    for (int e = 0; e < NE; ++e) {
      float v = red[0][e] + red[1][e] + red[2][e] + red[3][e];
      if (e == base) v += 10.0f;
      if (v > best) { best = v; bi = e; }
    }
    eid[t] = bi;
  }
}

// ---------------- bucket tokens + worklist ----------------
__global__ void k_init(int* counts, int* cursors) {
  int i = threadIdx.x;
  if (i < NE) { counts[i] = 0; cursors[i] = 0; }
}
__global__ void k_hist(const int* __restrict__ eid, int* __restrict__ counts) {
  int t = blockIdx.x * 256 + threadIdx.x;
  if (t < NT) atomicAdd(&counts[eid[t]], 1);
}
__global__ void k_scan(const int* __restrict__ counts, int* __restrict__ offsets,
                       int* __restrict__ cursors, int* __restrict__ wk) {
  if (threadIdx.x == 0) {
    int s = 0;
    for (int e = 0; e < NE; ++e) { offsets[e] = s; cursors[e] = s; s += counts[e]; }
    offsets[NE] = s;
    int n = 0;
    for (int e = 0; e < NE; ++e) {
      int tiles = (counts[e] + 127) >> 7;
      for (int m = 0; m < tiles; ++m) { wk[n++] = e | (m << 8); }
    }
    wk[MAXITEMS] = n;
  }
}
__global__ void k_scatter(const int* __restrict__ eid, int* __restrict__ cursors,
                          int* __restrict__ tlist) {
  int t = blockIdx.x * 256 + threadIdx.x;
  if (t < NT) {
    int e = eid[t];
    int pos = atomicAdd(&cursors[e], 1);
    tlist[pos] = t;
  }
}

// ---------------- gemm1: h = silu(x@Wg) * (x@Wu) ----------------
// Pre-transposed+swizzled B tiles: stage = 4 linear gl_lds/wave, NO in-loop
// transpose. Quad-buffered Pb, 3-substep load flight (vmcnt 16), 1 barrier/step.
__global__ __launch_bounds__(256, 2) void k_gemm1(
    const unsigned short* __restrict__ xb, const unsigned short* __restrict__ wgb,
    const int* __restrict__ offsets, const int* __restrict__ tlist,
    const int* __restrict__ wk, unsigned short* __restrict__ hbuf) {
  int item = blockIdx.y;
  if (item >= wk[MAXITEMS]) return;
  int w = wk[item];
  int e = w & 255, tb = (w >> 8) * 128;
  int off = offsets[e], cnt = offsets[e + 1] - off;
  int cx = blockIdx.x;
  int c0 = cx * 64;

  __shared__ unsigned short Pb[4][2][4096];  // [buf][gate/up][64col x 64k swz] 64KB
  __shared__ int ltok[128];

  int tid = threadIdx.x, lane = tid & 63, wv = tid >> 6;
  if (tid < 128) { int r = tb + tid; if (r > cnt - 1) r = cnt - 1; ltok[tid] = tlist[off + r]; }
  __syncthreads();

  int lr = lane & 15, hi = lane >> 4, mb = wv * 32;
  const unsigned short* aRow0 = xb + (size_t)ltok[mb + lr] * HD + hi * 8;
  const unsigned short* aRow1 = xb + (size_t)ltok[mb + 16 + lr] * HD + hi * 8;

  int gu = wv >> 1, part = wv & 1;
  const unsigned short* wS =
      wgb + (((size_t)e * 16 + (gu ? 8 + cx : cx)) * 32) * 4096 + part * 2048 + lane * 8;

#define STAGEB(BUF) do { \
  gl_lds16(wS,        &Pb[BUF][gu][part * 2048]); \
  gl_lds16(wS + 512,  &Pb[BUF][gu][part * 2048 + 512]); \
  gl_lds16(wS + 1024, &Pb[BUF][gu][part * 2048 + 1024]); \
  gl_lds16(wS + 1536, &Pb[BUF][gu][part * 2048 + 1536]); \
  wS += 4096; } while (0)

  bf16x8_t A0[4], A1[4], A2[4], A3[4];
#define LOADA(SET, KT) do { \
  SET[0] = *(const bf16x8_t*)(aRow0 + (KT) * 64); \
  SET[1] = *(const bf16x8_t*)(aRow0 + (KT) * 64 + 32); \
  SET[2] = *(const bf16x8_t*)(aRow1 + (KT) * 64); \
  SET[3] = *(const bf16x8_t*)(aRow1 + (KT) * 64 + 32); } while (0)

  f32x4_t zero = {0.f, 0.f, 0.f, 0.f};
  f32x4_t accg[2][4], accu[2][4];
#pragma unroll
  for (int m = 0; m < 2; ++m)
#pragma unroll
    for (int n = 0; n < 4; ++n) { accg[m][n] = zero; accu[m][n] = zero; }

#define MFMA_PH(BUF, SET) do { \
  __builtin_amdgcn_s_setprio(1); \
  _Pragma("unroll") for (int kk = 0; kk < 2; ++kk) { \
    int cidx = kk * 4 + hi; \
    bf16x8_t a0 = SET[kk], a1 = SET[2 + kk]; \
    _Pragma("unroll") for (int n = 0; n < 4; ++n) { \
      int r = n * 16 + lr; \
      int o = r * 64 + ((cidx ^ (r & 7)) * 8); \
      bf16x8_t bg = *(bf16x8_t*)&Pb[BUF][0][o]; \
      bf16x8_t bu = *(bf16x8_t*)&Pb[BUF][1][o]; \
      accg[0][n] = __builtin_amdgcn_mfma_f32_16x16x32_bf16(a0, bg, accg[0][n], 0, 0, 0); \
      accu[0][n] = __builtin_amdgcn_mfma_f32_16x16x32_bf16(a0, bu, accu[0][n], 0, 0, 0); \
      accg[1][n] = __builtin_amdgcn_mfma_f32_16x16x32_bf16(a1, bg, accg[1][n], 0, 0, 0); \
      accu[1][n] = __builtin_amdgcn_mfma_f32_16x16x32_bf16(a1, bu, accu[1][n], 0, 0, 0); \
    } } \
  __builtin_amdgcn_s_setprio(0); } while (0)

#define SUBSTEP(KT, BUF, SETC, SETN, VMC) do { \
  asm volatile("s_waitcnt vmcnt(" #VMC ")" ::: "memory"); \
  __builtin_amdgcn_sched_barrier(0); \
  __builtin_amdgcn_s_barrier(); \
  MFMA_PH(BUF, SETC); \
  if ((KT) + 3 < 32) { LOADA(SETN, (KT) + 3); STAGEB(((BUF) + 3) & 3); } \
} while (0)

  LOADA(A0, 0); STAGEB(0);
  LOADA(A1, 1); STAGEB(1);
  LOADA(A2, 2); STAGEB(2);

  for (int g = 0; g < 7; ++g) {
    int k4 = g * 4;
    SUBSTEP(k4 + 0, 0, A0, A3, 16);
    SUBSTEP(k4 + 1, 1, A1, A0, 16);
    SUBSTEP(k4 + 2, 2, A2, A1, 16);
    SUBSTEP(k4 + 3, 3, A3, A2, 16);
  }
  SUBSTEP(28, 0, A0, A3, 16);
  SUBSTEP(29, 1, A1, A0, 16);
  SUBSTEP(30, 2, A2, A1, 8);
  SUBSTEP(31, 3, A3, A2, 0);

#undef SUBSTEP
#undef MFMA_PH
#undef LOADA
#undef STAGEB

  int rq = hi * 4;
#pragma unroll
  for (int m = 0; m < 2; ++m)
#pragma unroll
    for (int n = 0; n < 4; ++n)
#pragma unroll
      for (int j = 0; j < 4; ++j) {
        int r = tb + mb + m * 16 + rq + j;
        if (r < cnt) {
          float g = accg[m][n][j], u = accu[m][n][j];
          float hv = (g / (1.f + __expf(-g))) * u;
          hbuf[(size_t)(off + r) * ID + c0 + n * 16 + lr] = f2bf(hv);
        }
      }
}

// ---------------- gemm2: out = h @ Wd ----------------
// 128 tokens x 128 out-cols (tiles cb=2cx, 2cx+1); 8 K-steps, same pipeline.
__global__ __launch_bounds__(256, 2) void k_gemm2(
    const unsigned short* __restrict__ hbuf, const unsigned short* __restrict__ wdb,
    const int* __restrict__ offsets, const int* __restrict__ tlist,
    const int* __restrict__ wk, float* __restrict__ out) {
  int item = blockIdx.y;
  if (item >= wk[MAXITEMS]) return;
  int w = wk[item];
  int e = w & 255, tb = (w >> 8) * 128;
  int off = offsets[e], cnt = offsets[e + 1] - off;
  int cx = blockIdx.x;
  int c0 = cx * 128;

  __shared__ unsigned short Pb[4][2][4096];

  int tid = threadIdx.x, lane = tid & 63, wv = tid >> 6;
  int lr = lane & 15, hi = lane >> 4, mb = wv * 32;

  int r0 = tb + mb + lr;      if (r0 > cnt - 1) r0 = cnt - 1;
  int r1 = tb + mb + 16 + lr; if (r1 > cnt - 1) r1 = cnt - 1;
  const unsigned short* aRow0 = hbuf + (size_t)(off + r0) * ID + hi * 8;
  const unsigned short* aRow1 = hbuf + (size_t)(off + r1) * ID + hi * 8;

  int gu = wv >> 1, part = wv & 1;
  const unsigned short* wS =
      wdb + (((size_t)e * 32 + 2 * cx + gu) * 8) * 4096 + part * 2048 + lane * 8;

#define STAGEB(BUF) do { \
  gl_lds16(wS,        &Pb[BUF][gu][part * 2048]); \
  gl_lds16(wS + 512,  &Pb[BUF][gu][part * 2048 + 512]); \
  gl_lds16(wS + 1024, &Pb[BUF][gu][part * 2048 + 1024]); \
  gl_lds16(wS + 1536, &Pb[BUF][gu][part * 2048 + 1536]); \
  wS += 4096; } while (0)

  bf16x8_t A0[4], A1[4], A2[4], A3[4];
#define LOADA(SET, KT) do { \
  SET[0] = *(const bf16x8_t*)(aRow0 + (KT) * 64); \
  SET[1] = *(const bf16x8_t*)(aRow0 + (KT) * 64 + 32); \
  SET[2] = *(const bf16x8_t*)(aRow1 + (KT) * 64); \
  SET[3] = *(const bf16x8_t*)(aRow1 + (KT) * 64 + 32); } while (0)

  f32x4_t zero = {0.f, 0.f, 0.f, 0.f};
  f32x4_t acc[2][8];
#pragma unroll
  for (int m = 0; m < 2; ++m)
#pragma unroll
    for (int n = 0; n < 8; ++n) acc[m][n] = zero;

#define MFMA_PH(BUF, SET) do { \
  __builtin_amdgcn_s_setprio(1); \
  _Pragma("unroll") for (int kk = 0; kk < 2; ++kk) { \
    int cidx = kk * 4 + hi; \
    bf16x8_t a0 = SET[kk], a1 = SET[2 + kk]; \
    _Pragma("unroll") for (int n = 0; n < 8; ++n) { \
      int r = (n & 3) * 16 + lr; \
      int o = r * 64 + ((cidx ^ (r & 7)) * 8); \
      bf16x8_t b = *(bf16x8_t*)&Pb[BUF][n >> 2][o]; \
      acc[0][n] = __builtin_amdgcn_mfma_f32_16x16x32_bf16(a0, b, acc[0][n], 0, 0, 0); \
      acc[1][n] = __builtin_amdgcn_mfma_f32_16x16x32_bf16(a1, b, acc[1][n], 0, 0, 0); \
    } } \
  __builtin_amdgcn_s_setprio(0); } while (0)

#define SUBSTEP(KT, BUF, SETC, SETN, VMC) do { \
  asm volatile("s_waitcnt vmcnt(" #VMC ")" ::: "memory"); \
  __builtin_amdgcn_sched_barrier(0); \
  __builtin_amdgcn_s_barrier(); \
  MFMA_PH(BUF, SETC); \
  if ((KT) + 3 < 8) { LOADA(SETN, (KT) + 3); STAGEB(((BUF) + 3) & 3); } \
} while (0)

  LOADA(A0, 0); STAGEB(0);
  LOADA(A1, 1); STAGEB(1);
  LOADA(A2, 2); STAGEB(2);

  SUBSTEP(0, 0, A0, A3, 16);
  SUBSTEP(1, 1, A1, A0, 16);
  SUBSTEP(2, 2, A2, A1, 16);
  SUBSTEP(3, 3, A3, A2, 16);
  SUBSTEP(4, 0, A0, A3, 16);
  SUBSTEP(5, 1, A1, A0, 16);
  SUBSTEP(6, 2, A2, A1, 8);
  SUBSTEP(7, 3, A3, A2, 0);

#undef SUBSTEP
#undef MFMA_PH
#undef LOADA
#undef STAGEB

  int rq = hi * 4;
#pragma unroll
  for (int m = 0; m < 2; ++m)
#pragma unroll
    for (int n = 0; n < 8; ++n)
#pragma unroll
      for (int j = 0; j < 4; ++j) {
        int r = tb + mb + m * 16 + rq + j;
        if (r < cnt) {
          out[(size_t)tlist[off + r] * HD + c0 + n * 16 + lr] = acc[m][n][j];
        }
      }
}

extern "C" void kernel_launch(void* const* d_in, const int* in_sizes, int n_in,
                              void* d_out, int out_size, void* d_ws, size_t ws_size,
                              hipStream_t stream) {
  (void)in_sizes; (void)n_in; (void)out_size; (void)ws_size;
  const float* x   = (const float*)d_in[0];
  const int*   tok = (const int*)d_in[1];
  const float* mu  = (const float*)d_in[2];
  const float* gup = (const float*)d_in[3];
  const float* dwn = (const float*)d_in[4];
  const float* wr  = (const float*)d_in[5];
  float* out = (float*)d_out;

  char* ws = (char*)d_ws;
  int* eid     = (int*)ws;
  int* tlist   = (int*)(ws + 16384);
  int* counts  = (int*)(ws + 32768);
  int* offsets = (int*)(ws + 32896);
  int* cursors = (int*)(ws + 33024);
  int* wk      = (int*)(ws + 33152);
  unsigned short* xb   = (unsigned short*)(ws + 65536);                       // 16 MB
  unsigned short* hbuf = (unsigned short*)(ws + 65536 + 16777216);            // 4 MB
  unsigned short* wgb  = (unsigned short*)(ws + 65536 + 16777216 + 4194304);  // 64 MB
  unsigned short* wdb  = (unsigned short*)(ws + 65536 + 16777216 + 4194304 + 67108864); // 32 MB

  k_prep_gu<<<dim3(32, 16), 256, 0, stream>>>(gup, wgb);
  k_prep_dn<<<dim3(8, 16, 2), 256, 0, stream>>>(dwn, wdb);
  k_cast_x <<<4096, 256, 0, stream>>>(x, xb);
  k_route  <<<NT, 256, 0, stream>>>(mu, tok, wr, eid);
  k_init   <<<1, 64, 0, stream>>>(counts, cursors);
  k_hist   <<<16, 256, 0, stream>>>(eid, counts);
  k_scan   <<<1, 64, 0, stream>>>(counts, offsets, cursors, wk);
  k_scatter<<<16, 256, 0, stream>>>(eid, cursors, tlist);
  k_gemm1  <<<dim3(8, MAXITEMS), 256, 0, stream>>>(xb, wgb, offsets, tlist, wk, hbuf);
  k_gemm2  <<<dim3(16, MAXITEMS), 256, 0, stream>>>(hbuf, wdb, offsets, tlist, wk, out);
}

// Round 13
// 221.650 us; speedup vs baseline: 1.0570x; 1.0445x over previous
//
#include <hip/hip_runtime.h>
#include <hip/hip_bf16.h>

#define NT 4096
#define HD 2048
#define NE 16
#define ID 512
#define TWO_I 1024
#define LP 266       // prep LDS row pitch in ushorts (532B) -> 2-way max on u16 gather
#define MAXITEMS 47  // worst case: ceil(4081/128)=32 + 15 singleton experts

typedef __attribute__((ext_vector_type(8))) short bf16x8_t;
typedef __attribute__((ext_vector_type(4))) float f32x4_t;

__device__ __forceinline__ unsigned short f2bf(float f) {
  union { float f; unsigned int u; } v; v.f = f;
  unsigned int r = v.u + 0x7fffu + ((v.u >> 16) & 1u);
  return (unsigned short)(r >> 16);
}
__device__ __forceinline__ unsigned pk2(unsigned short a, unsigned short b) {
  return (unsigned)a | ((unsigned)b << 16);
}
// async global->LDS: LDS dest = wave-uniform base + lane*16; global src PER-LANE
__device__ __forceinline__ void gl_lds16(const void* g, void* l) {
  __builtin_amdgcn_global_load_lds(
      (const __attribute__((address_space(1))) unsigned int*)g,
      (__attribute__((address_space(3))) unsigned int*)l, 16, 0, 0);
}

// ============ weight prep: f32 [k][col] -> bf16 TRANSPOSED+SWIZZLED tiles =========
// layout: [e][cb][kt][ 64col x 64k tile ]; elem (c,k) at c*64 + ((k>>3)^(c&7))*8 + (k&7).
// Writes COALESCED: lane l emits chunk m=l&7 of col (l>>3)+8w -> 1KB/wave store.
__global__ __launch_bounds__(256) void k_prep_gu(const float* __restrict__ gup,
                                                 unsigned short* __restrict__ wgb) {
  int kt = blockIdx.x, e = blockIdx.y;           // grid (32, 16)
  int K0 = kt * 64;
  int t = threadIdx.x, w = t >> 6, lane = t & 63;
  __shared__ unsigned short L[64 * LP];          // [k][col 0..255]
  int cgrp = t >> 3, m = t & 7;
  int kc = m ^ (cgrp & 7);
  for (int q = 0; q < 4; ++q) {
    // stage: coalesced 1KB/wave reads, bf16 convert
    for (int rd = 0; rd < 16; ++rd) {
      int row = rd * 4 + w;
      const float* s = gup + ((size_t)e * HD + K0 + row) * TWO_I + q * 256 + lane * 4;
      float4 v = *(const float4*)s;
      uint2 p; p.x = pk2(f2bf(v.x), f2bf(v.y)); p.y = pk2(f2bf(v.z), f2bf(v.w));
      *(uint2*)&L[row * LP + lane * 4] = p;
    }
    __syncthreads();
    // gather (u16 column reads, swizzle folded into kc) + coalesced 1KB/wave stores
#pragma unroll
    for (int it = 0; it < 8; ++it) {
      int Cl = it * 32 + cgrp;
      int cb = q * 4 + (Cl >> 6), c = Cl & 63;
      const unsigned short* src = &L[(kc * 8) * LP + Cl];
      unsigned short tv[8];
#pragma unroll
      for (int j = 0; j < 8; ++j) tv[j] = src[j * LP];
      uint4 val;
      val.x = pk2(tv[0], tv[1]); val.y = pk2(tv[2], tv[3]);
      val.z = pk2(tv[4], tv[5]); val.w = pk2(tv[6], tv[7]);
      unsigned short* dst = wgb + (((size_t)e * 16 + cb) * 32 + kt) * 4096 + c * 64 + m * 8;
      *(uint4*)dst = val;
    }
    __syncthreads();
  }
}
__global__ __launch_bounds__(256) void k_prep_dn(const float* __restrict__ dwn,
                                                 unsigned short* __restrict__ wdb) {
  int kt = blockIdx.x, e = blockIdx.y, half = blockIdx.z;  // grid (8, 16, 2)
  int K0 = kt * 64;
  int t = threadIdx.x, w = t >> 6, lane = t & 63;
  __shared__ unsigned short L[64 * LP];
  int cgrp = t >> 3, m = t & 7;
  int kc = m ^ (cgrp & 7);
  for (int q = 0; q < 4; ++q) {
    for (int rd = 0; rd < 16; ++rd) {
      int row = rd * 4 + w;
      const float* s = dwn + ((size_t)e * ID + K0 + row) * HD + half * 1024 + q * 256 + lane * 4;
      float4 v = *(const float4*)s;
      uint2 p; p.x = pk2(f2bf(v.x), f2bf(v.y)); p.y = pk2(f2bf(v.z), f2bf(v.w));
      *(uint2*)&L[row * LP + lane * 4] = p;
    }
    __syncthreads();
#pragma unroll
    for (int it = 0; it < 8; ++it) {
      int Cl = it * 32 + cgrp;
      int cb = half * 16 + q * 4 + (Cl >> 6), c = Cl & 63;
      const unsigned short* src = &L[(kc * 8) * LP + Cl];
      unsigned short tv[8];
#pragma unroll
      for (int j = 0; j < 8; ++j) tv[j] = src[j * LP];
      uint4 val;
      val.x = pk2(tv[0], tv[1]); val.y = pk2(tv[2], tv[3]);
      val.z = pk2(tv[4], tv[5]); val.w = pk2(tv[6], tv[7]);
      unsigned short* dst = wdb + (((size_t)e * 32 + cb) * 8 + kt) * 4096 + c * 64 + m * 8;
      *(uint4*)dst = val;
    }
    __syncthreads();
  }
}

// ---------------- cast x (f32 -> bf16) ----------------
__global__ void k_cast_x(const float* __restrict__ x, unsigned short* __restrict__ xb) {
  size_t i = ((size_t)blockIdx.x * 256 + threadIdx.x) * 8;
  float4 a = *(const float4*)(x + i);
  float4 b = *(const float4*)(x + i + 4);
  uint4 pk;
  pk.x = pk2(f2bf(a.x), f2bf(a.y)); pk.y = pk2(f2bf(a.z), f2bf(a.w));
  pk.z = pk2(f2bf(b.x), f2bf(b.y)); pk.w = pk2(f2bf(b.z), f2bf(b.w));
  *(uint4*)(xb + i) = pk;
}

// ---------------- routing ----------------
__global__ void k_route(const float* __restrict__ mu, const int* __restrict__ tok,
                        const float* __restrict__ wr, int* __restrict__ eid) {
  int t = blockIdx.x;
  int tid = threadIdx.x;
  float p[NE];
#pragma unroll
  for (int e = 0; e < NE; ++e) p[e] = 0.f;
  const float* m = mu + (size_t)t * HD;
  for (int h = tid; h < HD; h += 256) {
    float mv = m[h];
#pragma unroll
    for (int e = 0; e < NE; ++e) p[e] += mv * wr[e * HD + h];
  }
#pragma unroll
  for (int e = 0; e < NE; ++e) {
    float v = p[e];
#pragma unroll
    for (int s = 32; s; s >>= 1) v += __shfl_xor(v, s, 64);
    p[e] = v;
  }
  __shared__ float red[4][NE];
  int lane = tid & 63, wv = tid >> 6;
  if (lane == 0) {
#pragma unroll
    for (int e = 0; e < NE; ++e) red[wv][e] = p[e];
  }
  __syncthreads();
  if (tid == 0) {
    int tk = tok[t];
    if (tk < 0) tk = 0;
    if (tk > 31999) tk = 31999;
    int base = tk & 15;
    float best = -3.0e38f; int bi = 0;
    for (int e = 0; e < NE; ++e) {
      float v = red[0][e] + red[1][e] + red[2][e] + red[3][e];
      if (e == base) v += 10.0f;
      if (v > best) { best = v; bi = e; }
    }
    eid[t] = bi;
  }
}

// ---------------- bucket tokens + worklist ----------------
__global__ void k_init(int* counts, int* cursors) {
  int i = threadIdx.x;
  if (i < NE) { counts[i] = 0; cursors[i] = 0; }
}
__global__ void k_hist(const int* __restrict__ eid, int* __restrict__ counts) {
  int t = blockIdx.x * 256 + threadIdx.x;
  if (t < NT) atomicAdd(&counts[eid[t]], 1);
}
__global__ void k_scan(const int* __restrict__ counts, int* __restrict__ offsets,
                       int* __restrict__ cursors, int* __restrict__ wk) {
  if (threadIdx.x == 0) {
    int s = 0;
    for (int e = 0; e < NE; ++e) { offsets[e] = s; cursors[e] = s; s += counts[e]; }
    offsets[NE] = s;
    int n = 0;
    for (int e = 0; e < NE; ++e) {
      int tiles = (counts[e] + 127) >> 7;
      for (int m = 0; m < tiles; ++m) { wk[n++] = e | (m << 8); }
    }
    wk[MAXITEMS] = n;
  }
}
__global__ void k_scatter(const int* __restrict__ eid, int* __restrict__ cursors,
                          int* __restrict__ tlist) {
  int t = blockIdx.x * 256 + threadIdx.x;
  if (t < NT) {
    int e = eid[t];
    int pos = atomicAdd(&cursors[e], 1);
    tlist[pos] = t;
  }
}

// ---------------- gemm1: h = silu(x@Wg) * (x@Wu) ----------------
// Pre-transposed+swizzled B tiles: stage = 4 linear gl_lds/wave, NO in-loop
// transpose. Quad-buffered Pb, 3-substep load flight (vmcnt 16), 1 barrier/step.
__global__ __launch_bounds__(256, 2) void k_gemm1(
    const unsigned short* __restrict__ xb, const unsigned short* __restrict__ wgb,
    const int* __restrict__ offsets, const int* __restrict__ tlist,
    const int* __restrict__ wk, unsigned short* __restrict__ hbuf) {
  int item = blockIdx.y;
  if (item >= wk[MAXITEMS]) return;
  int w = wk[item];
  int e = w & 255, tb = (w >> 8) * 128;
  int off = offsets[e], cnt = offsets[e + 1] - off;
  int cx = blockIdx.x;
  int c0 = cx * 64;

  __shared__ unsigned short Pb[4][2][4096];  // [buf][gate/up][64col x 64k swz] 64KB
  __shared__ int ltok[128];

  int tid = threadIdx.x, lane = tid & 63, wv = tid >> 6;
  if (tid < 128) { int r = tb + tid; if (r > cnt - 1) r = cnt - 1; ltok[tid] = tlist[off + r]; }
  __syncthreads();

  int lr = lane & 15, hi = lane >> 4, mb = wv * 32;
  const unsigned short* aRow0 = xb + (size_t)ltok[mb + lr] * HD + hi * 8;
  const unsigned short* aRow1 = xb + (size_t)ltok[mb + 16 + lr] * HD + hi * 8;

  int gu = wv >> 1, part = wv & 1;
  const unsigned short* wS =
      wgb + (((size_t)e * 16 + (gu ? 8 + cx : cx)) * 32) * 4096 + part * 2048 + lane * 8;

#define STAGEB(BUF) do { \
  gl_lds16(wS,        &Pb[BUF][gu][part * 2048]); \
  gl_lds16(wS + 512,  &Pb[BUF][gu][part * 2048 + 512]); \
  gl_lds16(wS + 1024, &Pb[BUF][gu][part * 2048 + 1024]); \
  gl_lds16(wS + 1536, &Pb[BUF][gu][part * 2048 + 1536]); \
  wS += 4096; } while (0)

  bf16x8_t A0[4], A1[4], A2[4], A3[4];
#define LOADA(SET, KT) do { \
  SET[0] = *(const bf16x8_t*)(aRow0 + (KT) * 64); \
  SET[1] = *(const bf16x8_t*)(aRow0 + (KT) * 64 + 32); \
  SET[2] = *(const bf16x8_t*)(aRow1 + (KT) * 64); \
  SET[3] = *(const bf16x8_t*)(aRow1 + (KT) * 64 + 32); } while (0)

  f32x4_t zero = {0.f, 0.f, 0.f, 0.f};
  f32x4_t accg[2][4], accu[2][4];
#pragma unroll
  for (int m = 0; m < 2; ++m)
#pragma unroll
    for (int n = 0; n < 4; ++n) { accg[m][n] = zero; accu[m][n] = zero; }

#define MFMA_PH(BUF, SET) do { \
  __builtin_amdgcn_s_setprio(1); \
  _Pragma("unroll") for (int kk = 0; kk < 2; ++kk) { \
    int cidx = kk * 4 + hi; \
    bf16x8_t a0 = SET[kk], a1 = SET[2 + kk]; \
    _Pragma("unroll") for (int n = 0; n < 4; ++n) { \
      int r = n * 16 + lr; \
      int o = r * 64 + ((cidx ^ (r & 7)) * 8); \
      bf16x8_t bg = *(bf16x8_t*)&Pb[BUF][0][o]; \
      bf16x8_t bu = *(bf16x8_t*)&Pb[BUF][1][o]; \
      accg[0][n] = __builtin_amdgcn_mfma_f32_16x16x32_bf16(a0, bg, accg[0][n], 0, 0, 0); \
      accu[0][n] = __builtin_amdgcn_mfma_f32_16x16x32_bf16(a0, bu, accu[0][n], 0, 0, 0); \
      accg[1][n] = __builtin_amdgcn_mfma_f32_16x16x32_bf16(a1, bg, accg[1][n], 0, 0, 0); \
      accu[1][n] = __builtin_amdgcn_mfma_f32_16x16x32_bf16(a1, bu, accu[1][n], 0, 0, 0); \
    } } \
  __builtin_amdgcn_s_setprio(0); } while (0)

#define SUBSTEP(KT, BUF, SETC, SETN, VMC) do { \
  asm volatile("s_waitcnt vmcnt(" #VMC ")" ::: "memory"); \
  __builtin_amdgcn_sched_barrier(0); \
  __builtin_amdgcn_s_barrier(); \
  MFMA_PH(BUF, SETC); \
  if ((KT) + 3 < 32) { LOADA(SETN, (KT) + 3); STAGEB(((BUF) + 3) & 3); } \
} while (0)

  LOADA(A0, 0); STAGEB(0);
  LOADA(A1, 1); STAGEB(1);
  LOADA(A2, 2); STAGEB(2);

  for (int g = 0; g < 7; ++g) {
    int k4 = g * 4;
    SUBSTEP(k4 + 0, 0, A0, A3, 16);
    SUBSTEP(k4 + 1, 1, A1, A0, 16);
    SUBSTEP(k4 + 2, 2, A2, A1, 16);
    SUBSTEP(k4 + 3, 3, A3, A2, 16);
  }
  SUBSTEP(28, 0, A0, A3, 16);
  SUBSTEP(29, 1, A1, A0, 16);
  SUBSTEP(30, 2, A2, A1, 8);
  SUBSTEP(31, 3, A3, A2, 0);

#undef SUBSTEP
#undef MFMA_PH
#undef LOADA
#undef STAGEB

  int rq = hi * 4;
#pragma unroll
  for (int m = 0; m < 2; ++m)
#pragma unroll
    for (int n = 0; n < 4; ++n)
#pragma unroll
      for (int j = 0; j < 4; ++j) {
        int r = tb + mb + m * 16 + rq + j;
        if (r < cnt) {
          float g = accg[m][n][j], u = accu[m][n][j];
          float hv = (g / (1.f + __expf(-g))) * u;
          hbuf[(size_t)(off + r) * ID + c0 + n * 16 + lr] = f2bf(hv);
        }
      }
}

// ---------------- gemm2: out = h @ Wd ----------------
// 128 tokens x 128 out-cols (tiles cb=2cx, 2cx+1); 8 K-steps, same pipeline.
__global__ __launch_bounds__(256, 2) void k_gemm2(
    const unsigned short* __restrict__ hbuf, const unsigned short* __restrict__ wdb,
    const int* __restrict__ offsets, const int* __restrict__ tlist,
    const int* __restrict__ wk, float* __restrict__ out) {
  int item = blockIdx.y;
  if (item >= wk[MAXITEMS]) return;
  int w = wk[item];
  int e = w & 255, tb = (w >> 8) * 128;
  int off = offsets[e], cnt = offsets[e + 1] - off;
  int cx = blockIdx.x;
  int c0 = cx * 128;

  __shared__ unsigned short Pb[4][2][4096];

  int tid = threadIdx.x, lane = tid & 63, wv = tid >> 6;
  int lr = lane & 15, hi = lane >> 4, mb = wv * 32;

  int r0 = tb + mb + lr;      if (r0 > cnt - 1) r0 = cnt - 1;
  int r1 = tb + mb + 16 + lr; if (r1 > cnt - 1) r1 = cnt - 1;
  const unsigned short* aRow0 = hbuf + (size_t)(off + r0) * ID + hi * 8;
  const unsigned short* aRow1 = hbuf + (size_t)(off + r1) * ID + hi * 8;

  int gu = wv >> 1, part = wv & 1;
  const unsigned short* wS =
      wdb + (((size_t)e * 32 + 2 * cx + gu) * 8) * 4096 + part * 2048 + lane * 8;

#define STAGEB(BUF) do { \
  gl_lds16(wS,        &Pb[BUF][gu][part * 2048]); \
  gl_lds16(wS + 512,  &Pb[BUF][gu][part * 2048 + 512]); \
  gl_lds16(wS + 1024, &Pb[BUF][gu][part * 2048 + 1024]); \
  gl_lds16(wS + 1536, &Pb[BUF][gu][part * 2048 + 1536]); \
  wS += 4096; } while (0)

  bf16x8_t A0[4], A1[4], A2[4], A3[4];
#define LOADA(SET, KT) do { \
  SET[0] = *(const bf16x8_t*)(aRow0 + (KT) * 64); \
  SET[1] = *(const bf16x8_t*)(aRow0 + (KT) * 64 + 32); \
  SET[2] = *(const bf16x8_t*)(aRow1 + (KT) * 64); \
  SET[3] = *(const bf16x8_t*)(aRow1 + (KT) * 64 + 32); } while (0)

  f32x4_t zero = {0.f, 0.f, 0.f, 0.f};
  f32x4_t acc[2][8];
#pragma unroll
  for (int m = 0; m < 2; ++m)
#pragma unroll
    for (int n = 0; n < 8; ++n) acc[m][n] = zero;

#define MFMA_PH(BUF, SET) do { \
  __builtin_amdgcn_s_setprio(1); \
  _Pragma("unroll") for (int kk = 0; kk < 2; ++kk) { \
    int cidx = kk * 4 + hi; \
    bf16x8_t a0 = SET[kk], a1 = SET[2 + kk]; \
    _Pragma("unroll") for (int n = 0; n < 8; ++n) { \
      int r = (n & 3) * 16 + lr; \
      int o = r * 64 + ((cidx ^ (r & 7)) * 8); \
      bf16x8_t b = *(bf16x8_t*)&Pb[BUF][n >> 2][o]; \
      acc[0][n] = __builtin_amdgcn_mfma_f32_16x16x32_bf16(a0, b, acc[0][n], 0, 0, 0); \
      acc[1][n] = __builtin_amdgcn_mfma_f32_16x16x32_bf16(a1, b, acc[1][n], 0, 0, 0); \
    } } \
  __builtin_amdgcn_s_setprio(0); } while (0)

#define SUBSTEP(KT, BUF, SETC, SETN, VMC) do { \
  asm volatile("s_waitcnt vmcnt(" #VMC ")" ::: "memory"); \
  __builtin_amdgcn_sched_barrier(0); \
  __builtin_amdgcn_s_barrier(); \
  MFMA_PH(BUF, SETC); \
  if ((KT) + 3 < 8) { LOADA(SETN, (KT) + 3); STAGEB(((BUF) + 3) & 3); } \
} while (0)

  LOADA(A0, 0); STAGEB(0);
  LOADA(A1, 1); STAGEB(1);
  LOADA(A2, 2); STAGEB(2);

  SUBSTEP(0, 0, A0, A3, 16);
  SUBSTEP(1, 1, A1, A0, 16);
  SUBSTEP(2, 2, A2, A1, 16);
  SUBSTEP(3, 3, A3, A2, 16);
  SUBSTEP(4, 0, A0, A3, 16);
  SUBSTEP(5, 1, A1, A0, 16);
  SUBSTEP(6, 2, A2, A1, 8);
  SUBSTEP(7, 3, A3, A2, 0);

#undef SUBSTEP
#undef MFMA_PH
#undef LOADA
#undef STAGEB

  int rq = hi * 4;
#pragma unroll
  for (int m = 0; m < 2; ++m)
#pragma unroll
    for (int n = 0; n < 8; ++n)
#pragma unroll
      for (int j = 0; j < 4; ++j) {
        int r = tb + mb + m * 16 + rq + j;
        if (r < cnt) {
          out[(size_t)tlist[off + r] * HD + c0 + n * 16 + lr] = acc[m][n][j];
        }
      }
}

extern "C" void kernel_launch(void* const* d_in, const int* in_sizes, int n_in,
                              void* d_out, int out_size, void* d_ws, size_t ws_size,
                              hipStream_t stream) {
  (void)in_sizes; (void)n_in; (void)out_size; (void)ws_size;
  const float* x   = (const float*)d_in[0];
  const int*   tok = (const int*)d_in[1];
  const float* mu  = (const float*)d_in[2];
  const float* gup = (const float*)d_in[3];
  const float* dwn = (const float*)d_in[4];
  const float* wr  = (const float*)d_in[5];
  float* out = (float*)d_out;

  char* ws = (char*)d_ws;
  int* eid     = (int*)ws;
  int* tlist   = (int*)(ws + 16384);
  int* counts  = (int*)(ws + 32768);
  int* offsets = (int*)(ws + 32896);
  int* cursors = (int*)(ws + 33024);
  int* wk      = (int*)(ws + 33152);
  unsigned short* xb   = (unsigned short*)(ws + 65536);                       // 16 MB
  unsigned short* hbuf = (unsigned short*)(ws + 65536 + 16777216);            // 4 MB
  unsigned short* wgb  = (unsigned short*)(ws + 65536 + 16777216 + 4194304);  // 64 MB
  unsigned short* wdb  = (unsigned short*)(ws + 65536 + 16777216 + 4194304 + 67108864); // 32 MB

  k_prep_gu<<<dim3(32, 16), 256, 0, stream>>>(gup, wgb);
  k_prep_dn<<<dim3(8, 16, 2), 256, 0, stream>>>(dwn, wdb);
  k_cast_x <<<4096, 256, 0, stream>>>(x, xb);
  k_route  <<<NT, 256, 0, stream>>>(mu, tok, wr, eid);
  k_init   <<<1, 64, 0, stream>>>(counts, cursors);
  k_hist   <<<16, 256, 0, stream>>>(eid, counts);
  k_scan   <<<1, 64, 0, stream>>>(counts, offsets, cursors, wk);
  k_scatter<<<16, 256, 0, stream>>>(eid, cursors, tlist);
  k_gemm1  <<<dim3(8, MAXITEMS), 256, 0, stream>>>(xb, wgb, offsets, tlist, wk, hbuf);
  k_gemm2  <<<dim3(16, MAXITEMS), 256, 0, stream>>>(hbuf, wdb, offsets, tlist, wk, out);
}